// Round 2
// baseline (578.413 us; speedup 1.0000x reference)
//
#include <hip/hip_runtime.h>
#include <cstdint>
#include <cstddef>

#define NUM_TOK 16384
#define HID     4096
#define NEXP    64
#define TOPK    8

// ---------------- transpose W [E][H] -> Wt [H][E] (1 MiB, L2-resident) ----------------
__global__ __launch_bounds__(256) void transpose_w(const float* __restrict__ W,
                                                   float* __restrict__ Wt) {
    int id4 = blockIdx.x * 256 + threadIdx.x;
    int e   = id4 >> 10;
    int k   = (id4 & 1023) << 2;
    float4 w = reinterpret_cast<const float4*>(W)[id4];
    Wt[(size_t)(k + 0) * NEXP + e] = w.x;
    Wt[(size_t)(k + 1) * NEXP + e] = w.y;
    Wt[(size_t)(k + 2) * NEXP + e] = w.z;
    Wt[(size_t)(k + 3) * NEXP + e] = w.w;
}

__device__ __forceinline__ float wave_sum(float v) {
#pragma unroll
    for (int off = 32; off >= 1; off >>= 1)
        v += __shfl_xor(v, off, 64);
    return v;
}

// ---------------- fused router ----------------
// grid 256 blocks x 512 threads (8 waves). Block owns 64 tokens.
// Wave w: k-slice s = w&3 (k in [s*1024, s*1024+1024)), token half h = w>>2.
// Lane tile: 4 tokens x 8 experts (outer product in registers):
//   lr = lane>>3 -> tokens h*32 + lr*4 .. +3;  lc = lane&7 -> experts lc*8 .. +7.
// Operands straight from cache: X per-row float4 (8-lane broadcast, L1-resident lines),
// W from L2-resident Wt [H][E] (float4 pairs). 12 loads per 128 FMA instructions.
// NUMERICS (R0-proven, ksplit=4): per (t,e): chunk = 64-k fmaf chain (part),
// slice = 16 chunks summed ascending (sl += part), total = ((s0+s1)+s2)+s3.
__global__ __launch_bounds__(512, 2) void router_fused(
    const float* __restrict__ hidden,   // [T][H]
    const float* __restrict__ Wt,       // [H][E]
    float* __restrict__ out_idx, float* __restrict__ out_gates,
    float* __restrict__ gImp, float* __restrict__ gCnt) {
    __shared__ float LDSp[4][64][65];   // 66,560 B: slice partials [s][t][e]

    const int tid  = threadIdx.x;
    const int lane = tid & 63;
    const int wave = __builtin_amdgcn_readfirstlane(tid >> 6);
    const int s    = wave & 3;          // k-slice
    const int h    = wave >> 2;         // token half
    const int lr   = lane >> 3;
    const int lc   = lane & 7;
    const int T0   = blockIdx.x * 64;
    const int t0   = h * 32 + lr * 4;   // block-local token base of this lane
    const int e0   = lc * 8;

    const float* xb0 = hidden + (size_t)(T0 + t0 + 0) * HID + s * 1024;
    const float* xb1 = hidden + (size_t)(T0 + t0 + 1) * HID + s * 1024;
    const float* xb2 = hidden + (size_t)(T0 + t0 + 2) * HID + s * 1024;
    const float* xb3 = hidden + (size_t)(T0 + t0 + 3) * HID + s * 1024;
    const float* wb  = Wt + (size_t)(s * 1024) * NEXP + e0;

    float sl[4][8];
#pragma unroll
    for (int i = 0; i < 4; ++i)
#pragma unroll
        for (int j = 0; j < 8; ++j) sl[i][j] = 0.0f;

    for (int c = 0; c < 16; ++c) {              // 16 chunks of 64 k per slice
        const int xoff = c * 64;
        const float* wc = wb + (size_t)c * 64 * NEXP;

        float part[4][8];
#pragma unroll
        for (int i = 0; i < 4; ++i)
#pragma unroll
            for (int j = 0; j < 8; ++j) part[i][j] = 0.0f;

#pragma unroll
        for (int k4 = 0; k4 < 16; ++k4) {
            float4 xv0 = *reinterpret_cast<const float4*>(xb0 + xoff + k4 * 4);
            float4 xv1 = *reinterpret_cast<const float4*>(xb1 + xoff + k4 * 4);
            float4 xv2 = *reinterpret_cast<const float4*>(xb2 + xoff + k4 * 4);
            float4 xv3 = *reinterpret_cast<const float4*>(xb3 + xoff + k4 * 4);
            float xa[4][4] = {{xv0.x, xv0.y, xv0.z, xv0.w},
                              {xv1.x, xv1.y, xv1.z, xv1.w},
                              {xv2.x, xv2.y, xv2.z, xv2.w},
                              {xv3.x, xv3.y, xv3.z, xv3.w}};
#pragma unroll
            for (int j2 = 0; j2 < 4; ++j2) {    // k = c*64 + k4*4 + j2, ascending
                float4 wA = *reinterpret_cast<const float4*>(wc + (size_t)(k4 * 4 + j2) * NEXP);
                float4 wB = *reinterpret_cast<const float4*>(wc + (size_t)(k4 * 4 + j2) * NEXP + 4);
                float wv[8] = {wA.x, wA.y, wA.z, wA.w, wB.x, wB.y, wB.z, wB.w};
#pragma unroll
                for (int i = 0; i < 4; ++i) {
                    float x = xa[i][j2];
#pragma unroll
                    for (int j = 0; j < 8; ++j)
                        part[i][j] = fmaf(x, wv[j], part[i][j]);   // k-ascending chain
                }
            }
        }
#pragma unroll
        for (int i = 0; i < 4; ++i)
#pragma unroll
            for (int j = 0; j < 8; ++j) sl[i][j] += part[i][j];    // two-level sum
    }

    // slice partials -> LDS
#pragma unroll
    for (int i = 0; i < 4; ++i)
#pragma unroll
        for (int j = 0; j < 8; ++j)
            LDSp[s][t0 + i][e0 + j] = sl[i][j];
    __syncthreads();

    // -------- epilogue: wave 0, lane = token (R0-proven finalize) --------
    if (wave == 0) {
        const int t = lane;
        float sc[NEXP];
#pragma unroll
        for (int e = 0; e < NEXP; ++e) {
            float v = LDSp[0][t][e];            // ascending slice fold: ((s0+s1)+s2)+s3
            v += LDSp[1][t][e];
            v += LDSp[2][t][e];
            v += LDSp[3][t][e];
            sc[e] = v;
        }

        float m = sc[0];
#pragma unroll
        for (int e = 1; e < NEXP; ++e) m = fmaxf(m, sc[e]);
        float sum = 0.0f;
#pragma unroll
        for (int e = 0; e < NEXP; ++e) { sc[e] = expf(sc[e] - m); sum += sc[e]; }
#pragma unroll
        for (int e = 0; e < NEXP; ++e) sc[e] = sc[e] / sum;        // softmax scores

        // top-8: masked argmax, strict '>', ascending e => lowest index on ties
        unsigned long long used = 0ull;
        float g[TOPK];
        float fid[TOPK];
#pragma unroll
        for (int r = 0; r < TOPK; ++r) {
            float best = -1.0f;
            int   bi   = 0;
#pragma unroll
            for (int e = 0; e < NEXP; ++e) {
                bool ok = (((used >> e) & 1ull) == 0ull) && (sc[e] > best);
                best = ok ? sc[e] : best;
                bi   = ok ? e : bi;
            }
            used |= (1ull << bi);
            g[r]   = best;
            fid[r] = (float)bi;
        }
        float gsum = ((g[0] + g[1]) + (g[2] + g[3])) +
                     ((g[4] + g[5]) + (g[6] + g[7])) + 1e-6f;
        float inv = 1.0f / gsum;

        int tg = T0 + t;
        float4 i0 = make_float4(fid[0], fid[1], fid[2], fid[3]);
        float4 i1 = make_float4(fid[4], fid[5], fid[6], fid[7]);
        float4 g0 = make_float4(g[0] * inv, g[1] * inv, g[2] * inv, g[3] * inv);
        float4 g1 = make_float4(g[4] * inv, g[5] * inv, g[6] * inv, g[7] * inv);
        *reinterpret_cast<float4*>(out_idx   + (size_t)tg * 8)     = i0;
        *reinterpret_cast<float4*>(out_idx   + (size_t)tg * 8 + 4) = i1;
        *reinterpret_cast<float4*>(out_gates + (size_t)tg * 8)     = g0;
        *reinterpret_cast<float4*>(out_gates + (size_t)tg * 8 + 4) = g1;

        // importance (sum of scores per expert) + counts across the 64 tokens
        float myImp = 0.0f, myCnt = 0.0f;
#pragma unroll
        for (int e = 0; e < NEXP; ++e) {
            float se = wave_sum(sc[e]);
            unsigned long long b = __ballot(((used >> e) & 1ull) != 0ull);
            if (lane == e) { myImp = se; myCnt = (float)__popcll(b); }
        }
        atomicAdd(&gImp[lane], myImp);
        atomicAdd(&gCnt[lane], myCnt);
    }
}

// ---------------- aux loss ----------------
__global__ __launch_bounds__(64) void aux_kernel(const float* __restrict__ gImp,
                                                 const float* __restrict__ gCnt,
                                                 float* __restrict__ out_aux) {
    int lane = threadIdx.x;
    float v = gImp[lane] * gCnt[lane];
    v = wave_sum(v);
    if (lane == 0)
        *out_aux = v * (0.01f / (float)NUM_TOK);
}

extern "C" void kernel_launch(void* const* d_in, const int* in_sizes, int n_in,
                              void* d_out, int out_size, void* d_ws, size_t ws_size,
                              hipStream_t stream) {
    const float* hidden = (const float*)d_in[0];   // [4,4096,4096] f32
    const float* W      = (const float*)d_in[1];   // [64,4096] f32

    float* out       = (float*)d_out;
    float* out_idx   = out;
    float* out_gates = out + (size_t)NUM_TOK * TOPK;
    float* out_aux   = out + (size_t)2 * NUM_TOK * TOPK;

    float* Wt   = (float*)d_ws;                          // 1 MiB
    float* gImp = (float*)((char*)d_ws + (1 << 20));     // 64 f32
    float* gCnt = gImp + NEXP;

    // NOTE: no ws_size-dependent branching — identical work on every call.
    hipMemsetAsync(gImp, 0, 2 * NEXP * sizeof(float), stream);
    transpose_w<<<256, 256, 0, stream>>>(W, Wt);
    router_fused<<<NUM_TOK / 64, 512, 0, stream>>>(hidden, Wt, out_idx, out_gates,
                                                   gImp, gCnt);
    aux_kernel<<<1, 64, 0, stream>>>(gImp, gCnt, out_aux);
}

// Round 3
// 497.658 us; speedup vs baseline: 1.1623x; 1.1623x over previous
//
#include <hip/hip_runtime.h>
#include <cstdint>
#include <cstddef>

#define NUM_TOK 16384
#define HID     4096
#define NEXP    64
#define TOPK    8
#define TB      32              // tokens per block
#define XPAD    68              // X row stride in floats: 16B-aligned, bank-spread

typedef const float __attribute__((address_space(1)))* gptr_t;
typedef float __attribute__((address_space(3)))* lptr_t;

// ---------------- transpose W [E][H] -> Wt [H][E] (1 MiB, L2-resident) ----------------
__global__ __launch_bounds__(256) void transpose_w(const float* __restrict__ W,
                                                   float* __restrict__ Wt) {
    int id4 = blockIdx.x * 256 + threadIdx.x;
    int e   = id4 >> 10;
    int k   = (id4 & 1023) << 2;
    float4 w = reinterpret_cast<const float4*>(W)[id4];
    Wt[(size_t)(k + 0) * NEXP + e] = w.x;
    Wt[(size_t)(k + 1) * NEXP + e] = w.y;
    Wt[(size_t)(k + 2) * NEXP + e] = w.z;
    Wt[(size_t)(k + 3) * NEXP + e] = w.w;
}

__device__ __forceinline__ float wave_sum(float v) {
#pragma unroll
    for (int off = 32; off >= 1; off >>= 1)
        v += __shfl_xor(v, off, 64);
    return v;
}

// ---------------- fused router ----------------
// grid 512 x 256 thr (4 waves). Block owns 32 tokens, full K per thread.
// Lane tile: 1 token x 8 experts. Wave w owns tokens w*8..w*8+7 (lr = lane>>3),
// experts e0 = (lane&7)*8. Both X and W chunks DMA-staged into LDS
// (global_load_lds, double-buffered, one barrier per 64-k chunk) -> inner loop
// is pure ds_read + fmaf; VMEM pipe only does async staging.
// NUMERICS (R2-proven, FROZEN): per (t,e): chunk = 64-k fmaf chain (part),
// slice = 16 chunks summed ascending (sliceSum += part),
// total = ((s0+s1)+s2)+s3 folded ascending at c = 15/31/47/63.
__global__ __launch_bounds__(256, 2) void router_fused(
    const float* __restrict__ hidden,   // [T][H]
    const float* __restrict__ Wt,       // [H][E]
    float* __restrict__ out_idx, float* __restrict__ out_gates,
    float* __restrict__ gImp, float* __restrict__ gCnt) {
    __shared__ __align__(16) float Xs[2][TB * XPAD];    // 17.4 KB
    __shared__ __align__(16) float Wsh[2][64 * NEXP];   // 32 KB

    const int tid  = threadIdx.x;
    const int lane = tid & 63;
    const int wave = __builtin_amdgcn_readfirstlane(tid >> 6);
    const int lr   = lane >> 3;
    const int lc   = lane & 7;
    const int row  = wave * 8 + lr;     // block-local token of this lane
    const int e0   = lc * 8;
    const int T0   = blockIdx.x * TB;

    auto stage = [&](int c) {
        int buf = c & 1;
#pragma unroll
        for (int j = 0; j < 8; ++j) {                  // X: wave stages 8 token rows
            int r = wave * 8 + j;
            const float* src = hidden + (size_t)(T0 + r) * HID + c * 64 + lane;
            __builtin_amdgcn_global_load_lds((gptr_t)src,
                                             (lptr_t)(&Xs[buf][r * XPAD + lane]), 4, 0, 0);
        }
#pragma unroll
        for (int j = 0; j < 4; ++j) {                  // W: 16 KB contiguous, width 16
            int i = wave * 4 + j;
            const float* src = Wt + (size_t)c * (64 * NEXP) + i * 256 + lane * 4;
            __builtin_amdgcn_global_load_lds((gptr_t)src,
                                             (lptr_t)(&Wsh[buf][i * 256 + lane * 4]), 16, 0, 0);
        }
    };

    float part[8], sliceSum[8], total[8];
#pragma unroll
    for (int j = 0; j < 8; ++j) { sliceSum[j] = 0.0f; total[j] = 0.0f; }

    stage(0);
    for (int c = 0; c < 64; ++c) {
        __syncthreads();                 // drains stage(c); fences buffer reuse
        if (c + 1 < 64) stage(c + 1);
        const float* __restrict__ xrow = &Xs[c & 1][row * XPAD];
        const float* __restrict__ wb   = &Wsh[c & 1][0];

#pragma unroll
        for (int j = 0; j < 8; ++j) part[j] = 0.0f;

#pragma unroll
        for (int k4 = 0; k4 < 16; ++k4) {
            float4 x4 = *reinterpret_cast<const float4*>(xrow + k4 * 4);   // 8-row bcast
            float xa[4] = {x4.x, x4.y, x4.z, x4.w};
#pragma unroll
            for (int j2 = 0; j2 < 4; ++j2) {          // k = c*64 + k4*4 + j2, ascending
                float4 wA = *reinterpret_cast<const float4*>(wb + (k4 * 4 + j2) * NEXP + e0);
                float4 wB = *reinterpret_cast<const float4*>(wb + (k4 * 4 + j2) * NEXP + e0 + 4);
                float x = xa[j2];
                part[0] = fmaf(x, wA.x, part[0]);
                part[1] = fmaf(x, wA.y, part[1]);
                part[2] = fmaf(x, wA.z, part[2]);
                part[3] = fmaf(x, wA.w, part[3]);
                part[4] = fmaf(x, wB.x, part[4]);
                part[5] = fmaf(x, wB.y, part[5]);
                part[6] = fmaf(x, wB.z, part[6]);
                part[7] = fmaf(x, wB.w, part[7]);
            }
        }
#pragma unroll
        for (int j = 0; j < 8; ++j) sliceSum[j] += part[j];   // two-level sum

        if ((c & 15) == 15) {                         // slice boundary: fold ascending
            if (c < 16) {
#pragma unroll
                for (int j = 0; j < 8; ++j) total[j] = sliceSum[j];
            } else {
#pragma unroll
                for (int j = 0; j < 8; ++j) total[j] += sliceSum[j];
            }
#pragma unroll
            for (int j = 0; j < 8; ++j) sliceSum[j] = 0.0f;
        }
    }

    // -------- epilogue: logits -> LDS (reuse Xs[0], safe: buf0 idle since c=62) --------
    float* Ep = &Xs[0][0];
    *reinterpret_cast<float4*>(Ep + row * XPAD + e0) =
        make_float4(total[0], total[1], total[2], total[3]);
    *reinterpret_cast<float4*>(Ep + row * XPAD + e0 + 4) =
        make_float4(total[4], total[5], total[6], total[7]);
    __syncthreads();

    float sc[NEXP];
#pragma unroll
    for (int e = 0; e < NEXP; ++e) sc[e] = 0.0f;
    unsigned long long used = 0ull;

    if (tid < TB) {                      // thread t owns token t (all in wave 0)
        const float* srow = Ep + tid * XPAD;
#pragma unroll
        for (int e4 = 0; e4 < NEXP / 4; ++e4) {
            float4 v = *reinterpret_cast<const float4*>(srow + e4 * 4);
            sc[e4 * 4 + 0] = v.x;
            sc[e4 * 4 + 1] = v.y;
            sc[e4 * 4 + 2] = v.z;
            sc[e4 * 4 + 3] = v.w;
        }

        float m = sc[0];
#pragma unroll
        for (int e = 1; e < NEXP; ++e) m = fmaxf(m, sc[e]);
        float sum = 0.0f;
#pragma unroll
        for (int e = 0; e < NEXP; ++e) { sc[e] = expf(sc[e] - m); sum += sc[e]; }
#pragma unroll
        for (int e = 0; e < NEXP; ++e) sc[e] = sc[e] / sum;    // softmax scores

        // top-8: masked argmax, strict '>', ascending e => lowest index on ties
        float g[TOPK];
        float fid[TOPK];
#pragma unroll
        for (int r = 0; r < TOPK; ++r) {
            float best = -1.0f;
            int   bi   = 0;
#pragma unroll
            for (int e = 0; e < NEXP; ++e) {
                bool ok = (((used >> e) & 1ull) == 0ull) && (sc[e] > best);
                best = ok ? sc[e] : best;
                bi   = ok ? e : bi;
            }
            used |= (1ull << bi);
            g[r]   = best;
            fid[r] = (float)bi;
        }
        float gsum = ((g[0] + g[1]) + (g[2] + g[3])) +
                     ((g[4] + g[5]) + (g[6] + g[7])) + 1e-6f;
        float inv = 1.0f / gsum;

        int t = T0 + tid;
        float4 i0 = make_float4(fid[0], fid[1], fid[2], fid[3]);
        float4 i1 = make_float4(fid[4], fid[5], fid[6], fid[7]);
        float4 g0 = make_float4(g[0] * inv, g[1] * inv, g[2] * inv, g[3] * inv);
        float4 g1 = make_float4(g[4] * inv, g[5] * inv, g[6] * inv, g[7] * inv);
        *reinterpret_cast<float4*>(out_idx   + (size_t)t * 8)     = i0;
        *reinterpret_cast<float4*>(out_idx   + (size_t)t * 8 + 4) = i1;
        *reinterpret_cast<float4*>(out_gates + (size_t)t * 8)     = g0;
        *reinterpret_cast<float4*>(out_gates + (size_t)t * 8 + 4) = g1;
    }

    // aux: importance + counts over the block's 32 tokens (lanes >= 32: sc=0, used=0)
    if (wave == 0) {
        float myImp = 0.0f, myCnt = 0.0f;
#pragma unroll
        for (int e = 0; e < NEXP; ++e) {
            float se = wave_sum(sc[e]);
            unsigned long long b = __ballot(((used >> e) & 1ull) != 0ull);
            if (lane == e) { myImp = se; myCnt = (float)__popcll(b); }
        }
        atomicAdd(&gImp[lane], myImp);
        atomicAdd(&gCnt[lane], myCnt);
    }
}

// ---------------- aux loss ----------------
__global__ __launch_bounds__(64) void aux_kernel(const float* __restrict__ gImp,
                                                 const float* __restrict__ gCnt,
                                                 float* __restrict__ out_aux) {
    int lane = threadIdx.x;
    float v = gImp[lane] * gCnt[lane];
    v = wave_sum(v);
    if (lane == 0)
        *out_aux = v * (0.01f / (float)NUM_TOK);
}

extern "C" void kernel_launch(void* const* d_in, const int* in_sizes, int n_in,
                              void* d_out, int out_size, void* d_ws, size_t ws_size,
                              hipStream_t stream) {
    const float* hidden = (const float*)d_in[0];   // [4,4096,4096] f32
    const float* W      = (const float*)d_in[1];   // [64,4096] f32

    float* out       = (float*)d_out;
    float* out_idx   = out;
    float* out_gates = out + (size_t)NUM_TOK * TOPK;
    float* out_aux   = out + (size_t)2 * NUM_TOK * TOPK;

    float* Wt   = (float*)d_ws;                          // 1 MiB
    float* gImp = (float*)((char*)d_ws + (1 << 20));     // 64 f32
    float* gCnt = gImp + NEXP;

    // NOTE: no ws_size-dependent branching — identical work on every call.
    hipMemsetAsync(gImp, 0, 2 * NEXP * sizeof(float), stream);
    transpose_w<<<256, 256, 0, stream>>>(W, Wt);
    router_fused<<<NUM_TOK / TB, 256, 0, stream>>>(hidden, Wt, out_idx, out_gates,
                                                   gImp, gCnt);
    aux_kernel<<<1, 64, 0, stream>>>(gImp, gCnt, out_aux);
}